// Round 4
// baseline (216.417 us; speedup 1.0000x reference)
//
#include <hip/hip_runtime.h>
#include <hip/hip_bf16.h>
#include <stdint.h>

#define BB 2
#define TT 4096
#define CC 512
#define HH 8
#define MEM 256

typedef unsigned short u16;
typedef __bf16 bf16x8 __attribute__((ext_vector_type(8)));
typedef float floatx4 __attribute__((ext_vector_type(4)));

__device__ inline u16 f2bf(float f) {  // RNE
  uint32_t u = __float_as_uint(f);
  uint32_t r = (u + 0x7fffu + ((u >> 16) & 1u)) >> 16;
  return (u16)r;
}
__device__ inline u16 f2bf_r(float f) {  // round-half-up (2 ops), p>=0 only
  return (u16)((__float_as_uint(f) + 0x8000u) >> 16);
}

__device__ inline void gld16(const u16* g, u16* lds) {
  __builtin_amdgcn_global_load_lds(
      (const __attribute__((address_space(1))) uint32_t*)g,
      (__attribute__((address_space(3))) uint32_t*)lds, 16, 0, 0);
}

#define BARM() asm volatile("" ::: "memory")

// ---------------- fused fp32 -> bf16 convert (x, w_attn, w_proj) ----------
__global__ __launch_bounds__(256) void cvt_all(const float* __restrict__ x,
                                               const float* __restrict__ wa,
                                               const float* __restrict__ wp,
                                               u16* __restrict__ xb,
                                               u16* __restrict__ wab,
                                               u16* __restrict__ wpb) {
  int i = blockIdx.x * 256 + threadIdx.x;  // chunk of 4 floats
  const float* s; u16* d; int off;
  if (i < 1048576) { s = x; d = xb; off = i; }
  else if (i < 1245184) { s = wa; d = wab; off = i - 1048576; }
  else { s = wp; d = wpb; off = i - 1245184; }
  float4 v = *reinterpret_cast<const float4*>(s + (size_t)off * 4);
  ushort4 o;
  o.x = f2bf(v.x); o.y = f2bf(v.y); o.z = f2bf(v.z); o.w = f2bf(v.w);
  *reinterpret_cast<ushort4*>(d + (size_t)off * 4) = o;
}

// ================= 256x256 8-phase GEMM: C[M,N] = A[M,K] * Bw[N,K]^T =======
// PROFILING ROUND: in-kernel repeat (reps arg) to lift this dispatch above
// the 43.6us fill cutoff so its counters appear in top-5. Output identical:
// acc re-zeroed per rep, single C-write at the end.
__device__ inline void stage_hA(const u16* __restrict__ G, u16* lds, int K,
                                int gr0, int koff, int half, int wv, int lane) {
#pragma unroll
  for (int j = 0; j < 2; j++) {
    int lrow = (j * 8 + wv) * 8 + (lane >> 3);                 // 0..127
    int row = (lrow & 63) + ((lrow >> 6) << 7) + (half << 6);  // {0-63,128-191}+64*half
    int blk = (lane & 7) ^ (row & 7);
    gld16(G + (size_t)(gr0 + row) * K + koff + blk * 8,
          lds + (size_t)row * 64 + (lane & 7) * 8);
  }
}
__device__ inline void stage_hB(const u16* __restrict__ G, u16* lds, int K,
                                int gr0, int koff, int half, int wv, int lane) {
#pragma unroll
  for (int j = 0; j < 2; j++) {
    int lrow = (j * 8 + wv) * 8 + (lane >> 3);
    int row = (lrow & 31) + ((lrow >> 5) << 6) + (half << 5);  // 32-row stripes
    int blk = (lane & 7) ^ (row & 7);
    gld16(G + (size_t)(gr0 + row) * K + koff + blk * 8,
          lds + (size_t)row * 64 + (lane & 7) * 8);
  }
}

#define PHASE(MQ, NQ, STAGE, WAITV)                                            \
  {                                                                            \
    bf16x8 af[4][2], bfv[2][2];                                                \
    _Pragma("unroll") for (int fm = 0; fm < 4; fm++) {                         \
      int row = wm * 128 + MQ * 64 + fm * 16 + l16;                            \
      const u16* p = Ad + (size_t)row * 64;                                    \
      af[fm][0] = *(const bf16x8*)(p + ((quad ^ (row & 7)) << 3));             \
      af[fm][1] = *(const bf16x8*)(p + (((4 + quad) ^ (row & 7)) << 3));       \
    }                                                                          \
    _Pragma("unroll") for (int fn = 0; fn < 2; fn++) {                         \
      int row = wn * 64 + NQ * 32 + fn * 16 + l16;                             \
      const u16* p = Bd + (size_t)row * 64;                                    \
      bfv[fn][0] = *(const bf16x8*)(p + ((quad ^ (row & 7)) << 3));            \
      bfv[fn][1] = *(const bf16x8*)(p + (((4 + quad) ^ (row & 7)) << 3));      \
    }                                                                          \
    STAGE;                                                                     \
    BARM();                                                                    \
    __builtin_amdgcn_s_barrier();                                              \
    asm volatile("s_waitcnt lgkmcnt(0)" ::: "memory");                         \
    __builtin_amdgcn_sched_barrier(0);                                         \
    __builtin_amdgcn_s_setprio(1);                                             \
    _Pragma("unroll") for (int fm = 0; fm < 4; fm++)                           \
      _Pragma("unroll") for (int fn = 0; fn < 2; fn++) {                       \
        acc[MQ * 4 + fm][NQ * 2 + fn] =                                        \
            __builtin_amdgcn_mfma_f32_16x16x32_bf16(                           \
                af[fm][0], bfv[fn][0], acc[MQ * 4 + fm][NQ * 2 + fn], 0, 0, 0);\
        acc[MQ * 4 + fm][NQ * 2 + fn] =                                        \
            __builtin_amdgcn_mfma_f32_16x16x32_bf16(                           \
                af[fm][1], bfv[fn][1], acc[MQ * 4 + fm][NQ * 2 + fn], 0, 0, 0);\
      }                                                                        \
    __builtin_amdgcn_s_setprio(0);                                             \
    WAITV;                                                                     \
    BARM();                                                                    \
    __builtin_amdgcn_s_barrier();                                              \
    BARM();                                                                    \
  }

__global__ __launch_bounds__(512, 2) void gemm256(const u16* __restrict__ A,
                                                  const u16* __restrict__ Bw,
                                                  u16* __restrict__ C,
                                                  int M, int N, int K, int reps) {
  __shared__ __align__(16) u16 As[2][256 * 64];
  __shared__ __align__(16) u16 Bs[2][256 * 64];
  const int tid = threadIdx.x;
  const int lane = tid & 63, wv = tid >> 6;
  const int quad = lane >> 4, l16 = lane & 15;
  const int wm = wv >> 2, wn = wv & 3;

  // bijective XCD swizzle (nwg % 8 == 0 here: 192)
  const int nbx = N >> 8;
  const int nwg = (M >> 8) * nbx;
  int wg = blockIdx.x;
  if ((nwg & 7) == 0) wg = (wg & 7) * (nwg >> 3) + (wg >> 3);
  const int m0 = (wg / nbx) << 8, n0 = (wg % nbx) << 8;

  const int nK = K >> 6;
  floatx4 acc[8][4];

  for (int rep = 0; rep < reps; ++rep) {
#pragma unroll
    for (int mi = 0; mi < 8; mi++)
#pragma unroll
      for (int ni = 0; ni < 4; ni++)
#pragma unroll
        for (int r = 0; r < 4; r++) acc[mi][ni][r] = 0.f;

    // prologue: tile0 full + tile1 {A-mq0, B-nq0}
    stage_hA(A, As[0], K, m0, 0, 0, wv, lane);
    stage_hA(A, As[0], K, m0, 0, 1, wv, lane);
    stage_hB(Bw, Bs[0], K, n0, 0, 0, wv, lane);
    stage_hB(Bw, Bs[0], K, n0, 0, 1, wv, lane);
    if (nK > 1) {
      stage_hA(A, As[1], K, m0, 64, 0, wv, lane);
      stage_hB(Bw, Bs[1], K, n0, 64, 0, wv, lane);
      asm volatile("s_waitcnt vmcnt(4)" ::: "memory");
    } else {
      asm volatile("s_waitcnt vmcnt(0)" ::: "memory");
    }
    BARM();
    __builtin_amdgcn_s_barrier();
    BARM();

    for (int t = 0; t < nK; ++t) {
      const int d = t & 1;
      u16* Ad = As[d]; u16* Bd = Bs[d];
      u16* An = As[d ^ 1]; u16* Bn = Bs[d ^ 1];
      const int k1 = (t + 1) << 6, k2 = (t + 2) << 6;

      PHASE(0, 0, { if (t + 1 < nK) stage_hA(A, An, K, m0, k1, 1, wv, lane); }, {})
      PHASE(0, 1, { if (t + 1 < nK) stage_hB(Bw, Bn, K, n0, k1, 1, wv, lane); }, {})
      PHASE(1, 0, { if (t + 2 < nK) stage_hA(A, Ad, K, m0, k2, 0, wv, lane); }, {})
      PHASE(1, 1, { if (t + 2 < nK) stage_hB(Bw, Bd, K, n0, k2, 0, wv, lane); },
            { if (t + 2 < nK) asm volatile("s_waitcnt vmcnt(4)" ::: "memory");
              else            asm volatile("s_waitcnt vmcnt(0)" ::: "memory"); })
    }
  }

#pragma unroll
  for (int mi = 0; mi < 8; mi++) {
    int row = m0 + wm * 128 + mi * 16 + quad * 4;
#pragma unroll
    for (int ni = 0; ni < 4; ni++) {
      int col = n0 + wn * 64 + ni * 16 + l16;
#pragma unroll
      for (int r = 0; r < 4; r++)
        C[(size_t)(row + r) * N + col] = f2bf(acc[mi][ni][r]);
    }
  }
}

// ---------------- GEMM 128x64 (for N=512 proj: 512 blocks, 2/CU) ----------
__global__ __launch_bounds__(256) void gemm_bt_n64(const u16* __restrict__ A,
                                                   const u16* __restrict__ Bw,
                                                   float* __restrict__ C,
                                                   int M, int N, int K) {
  __shared__ __align__(16) u16 As[128 * 32];
  __shared__ __align__(16) u16 Bs[64 * 32];
  const int tid = threadIdx.x;
  const int w = tid >> 6, lane = tid & 63, quad = lane >> 4, l16 = lane & 15;
  const int m0 = blockIdx.x * 128, n0 = blockIdx.y * 64;

  floatx4 acc[2][4] = {};
  const int nK = K >> 5;
  for (int kb = 0; kb < nK; ++kb) {
    const int kof = kb * 32;
    {
      int c = tid;
      gld16(A + (size_t)(m0 + (c >> 2)) * K + kof + (c & 3) * 8, As + (size_t)c * 8);
      c = tid + 256;
      gld16(A + (size_t)(m0 + (c >> 2)) * K + kof + (c & 3) * 8, As + (size_t)c * 8);
      c = tid;
      gld16(Bw + (size_t)(n0 + (c >> 2)) * K + kof + (c & 3) * 8, Bs + (size_t)c * 8);
    }
    __syncthreads();
    bf16x8 af[2], bfr[4];
#pragma unroll
    for (int i = 0; i < 2; i++)
      af[i] = *reinterpret_cast<const bf16x8*>(&As[(w * 32 + i * 16 + l16) * 32 + quad * 8]);
#pragma unroll
    for (int i = 0; i < 4; i++)
      bfr[i] = *reinterpret_cast<const bf16x8*>(&Bs[(i * 16 + l16) * 32 + quad * 8]);
#pragma unroll
    for (int mi = 0; mi < 2; mi++)
#pragma unroll
      for (int ni = 0; ni < 4; ni++)
        acc[mi][ni] = __builtin_amdgcn_mfma_f32_16x16x32_bf16(af[mi], bfr[ni], acc[mi][ni], 0, 0, 0);
    __syncthreads();
  }
#pragma unroll
  for (int mi = 0; mi < 2; mi++) {
    int row = m0 + w * 32 + mi * 16 + quad * 4;
#pragma unroll
    for (int ni = 0; ni < 4; ni++) {
      int col = n0 + ni * 16 + l16;
#pragma unroll
      for (int r = 0; r < 4; r++)
        C[(size_t)(row + r) * N + col] = acc[mi][ni][r];
    }
  }
}

// ---------------- windowed flash attention, Tq=128 ----------------
// PROFILING ROUND: in-kernel repeat (reps arg); state re-zeroed per rep,
// identical output, ~reps x duration so counters surface in top-5.
__global__ __launch_bounds__(256, 2) void attn_win(const u16* __restrict__ qkv,
                                                   u16* __restrict__ y, int reps) {
  const int q0 = blockIdx.x * 128;
  const int h = blockIdx.y;
  const int b = blockIdx.z;
  const int tid = threadIdx.x;
  const int w = tid >> 6, lane = tid & 63, quad = lane >> 4, l16 = lane & 15;

  __shared__ __align__(16) u16 Qs[128 * 64];  // row-stride 64, col-block swizzled
  __shared__ __align__(16) u16 Ks[64 * 64];   // same
  __shared__ __align__(16) u16 Vt[64 * 72];   // V^T, stride 72, col = key^(d&56)
  __shared__ __align__(16) u16 Ps[4][32 * 72];

  // stage Q (128x64), swizzled
  const size_t baseQ = ((size_t)(b * TT + q0)) * 1536 + h * 64;
#pragma unroll
  for (int j = 0; j < 4; j++) {
    int c = tid + j * 256, row = c >> 3, blk = (c & 7) ^ (row & 7);
    gld16(qkv + baseQ + (size_t)row * 1536 + blk * 8, Qs + (size_t)c * 8);
  }
  __syncthreads();
  bf16x8 qf[2][2];
#pragma unroll
  for (int mi = 0; mi < 2; mi++) {
    int row = w * 32 + mi * 16 + l16;  // row&7 == l16&7
    qf[mi][0] = *reinterpret_cast<const bf16x8*>(&Qs[row * 64 + (quad ^ (l16 & 7)) * 8]);
    qf[mi][1] = *reinterpret_cast<const bf16x8*>(&Qs[row * 64 + ((quad + 4) ^ (l16 & 7)) * 8]);
#pragma unroll
    for (int e = 0; e < 8; e++) {  // fold 1/sqrt(d)=0.125 (exact pow2)
      qf[mi][0][e] = qf[mi][0][e] * (__bf16)0.125f;
      qf[mi][1][e] = qf[mi][1][e] * (__bf16)0.125f;
    }
  }

  floatx4 acc_o[2][4];
  float l_acc[2][4];

  const int s_min = (q0 >= 256) ? 0 : ((256 - q0) >> 6);
  const int key_v = tid >> 3, dc_v = tid & 7;       // this thread's V slot (half 0)
  const int key_v1 = (tid + 256) >> 3, dc_v1 = tid & 7;  // half 1

  for (int rep = 0; rep < reps; ++rep) {
#pragma unroll
    for (int mi = 0; mi < 2; mi++)
#pragma unroll
      for (int nt = 0; nt < 4; nt++) {
#pragma unroll
        for (int r = 0; r < 4; r++) acc_o[mi][nt][r] = 0.f;
        l_acc[mi][nt] = 0.f;
      }

    // prefetch V regs for first tile
    uint4 vp0, vp1;
    {
      size_t baseV = ((size_t)(b * TT + (q0 - 256 + s_min * 64))) * 1536 + 1024 + h * 64;
      vp0 = *reinterpret_cast<const uint4*>(qkv + baseV + (size_t)key_v * 1536 + dc_v * 8);
      vp1 = *reinterpret_cast<const uint4*>(qkv + baseV + (size_t)key_v1 * 1536 + dc_v1 * 8);
    }

    for (int s = s_min; s < 6; ++s) {
      const int k0 = q0 - 256 + s * 64;
      // stage K (swizzled DMA)
      const size_t baseK = ((size_t)(b * TT + k0)) * 1536 + 512 + h * 64;
      {
        int c = tid, row = c >> 3, blk = (c & 7) ^ (row & 7);
        gld16(qkv + baseK + (size_t)row * 1536 + blk * 8, Ks + (size_t)c * 8);
        c = tid + 256; row = c >> 3; blk = (c & 7) ^ (row & 7);
        gld16(qkv + baseK + (size_t)row * 1536 + blk * 8, Ks + (size_t)c * 8);
      }
      // write V^T from prefetched regs: elem (d,key) at Vt[d*72 + (key^(d&56))]
      {
        u16 tmp[8];
        *reinterpret_cast<uint4*>(tmp) = vp0;
        int col = key_v ^ (dc_v * 8);
#pragma unroll
        for (int e = 0; e < 8; e++) Vt[(dc_v * 8 + e) * 72 + col] = tmp[e];
        *reinterpret_cast<uint4*>(tmp) = vp1;
        col = key_v1 ^ (dc_v1 * 8);
#pragma unroll
        for (int e = 0; e < 8; e++) Vt[(dc_v1 * 8 + e) * 72 + col] = tmp[e];
      }
      // prefetch next tile's V regs (land during compute phase)
      if (s < 5) {
        size_t baseV = ((size_t)(b * TT + k0 + 64)) * 1536 + 1024 + h * 64;
        vp0 = *reinterpret_cast<const uint4*>(qkv + baseV + (size_t)key_v * 1536 + dc_v * 8);
        vp1 = *reinterpret_cast<const uint4*>(qkv + baseV + (size_t)key_v1 * 1536 + dc_v1 * 8);
      }
      __syncthreads();

      // wave-uniform mask mode: 0 none, 1 mask hq>kq, 2 mask hq<kq, 3 dead
      int mode = 0;
      if (s == 0) mode = (w < 2) ? 1 : 3;
      else if (s == 1) mode = (w < 2) ? 0 : 1;
      else if (s == 4) mode = (w < 2) ? 2 : 0;
      else if (s == 5) mode = (w < 2) ? 3 : 2;

      if (mode != 3) {
        bf16x8 bfr[4][2];
#pragma unroll
        for (int nt = 0; nt < 4; nt++) {
          int krow = nt * 16 + l16;
          bfr[nt][0] = *reinterpret_cast<const bf16x8*>(&Ks[krow * 64 + (quad ^ (l16 & 7)) * 8]);
          bfr[nt][1] = *reinterpret_cast<const bf16x8*>(&Ks[krow * 64 + ((quad + 4) ^ (l16 & 7)) * 8]);
        }
        floatx4 sc[2][4] = {};
#pragma unroll
        for (int mi = 0; mi < 2; mi++)
#pragma unroll
          for (int nt = 0; nt < 4; nt++) {
            sc[mi][nt] = __builtin_amdgcn_mfma_f32_16x16x32_bf16(qf[mi][0], bfr[nt][0], sc[mi][nt], 0, 0, 0);
            sc[mi][nt] = __builtin_amdgcn_mfma_f32_16x16x32_bf16(qf[mi][1], bfr[nt][1], sc[mi][nt], 0, 0, 0);
          }
        const int hqb = (w & 1) * 32 + quad * 4;  // + mi*16 + r
        if (mode == 1) {
#pragma unroll
          for (int mi = 0; mi < 2; mi++)
#pragma unroll
            for (int nt = 0; nt < 4; nt++)
#pragma unroll
              for (int r = 0; r < 4; r++)
                if (hqb + mi * 16 + r > nt * 16 + l16) sc[mi][nt][r] = -1e30f;
        } else if (mode == 2) {
#pragma unroll
          for (int mi = 0; mi < 2; mi++)
#pragma unroll
            for (int nt = 0; nt < 4; nt++)
#pragma unroll
              for (int r = 0; r < 4; r++)
                if (hqb + mi * 16 + r < nt * 16 + l16) sc[mi][nt][r] = -1e30f;
        }
        // fixed-max softmax: p = exp(s - 4); per-lane l accumulation
#pragma unroll
        for (int mi = 0; mi < 2; mi++)
#pragma unroll
          for (int nt = 0; nt < 4; nt++)
#pragma unroll
            for (int r = 0; r < 4; r++) {
              float p = __expf(sc[mi][nt][r] - 4.0f);
              l_acc[mi][r] += p;
              Ps[w][(mi * 16 + quad * 4 + r) * 72 + nt * 16 + l16] = f2bf_r(p);
            }
        // O += P*V
#pragma unroll
        for (int mi = 0; mi < 2; mi++)
#pragma unroll
          for (int ki = 0; ki < 2; ki++) {
            bf16x8 pf = *reinterpret_cast<const bf16x8*>(
                &Ps[w][(mi * 16 + l16) * 72 + ki * 32 + quad * 8]);
#pragma unroll
            for (int nt = 0; nt < 4; nt++) {
              int d = nt * 16 + l16;
              bf16x8 vf = *reinterpret_cast<const bf16x8*>(
                  &Vt[d * 72 + ((ki * 32 + quad * 8) ^ (d & 56))]);
              acc_o[mi][nt] = __builtin_amdgcn_mfma_f32_16x16x32_bf16(pf, vf, acc_o[mi][nt], 0, 0, 0);
            }
          }
      }
      __syncthreads();
    }
  }
  // epilogue: reduce l across the quad-row's 16 lanes, normalize, write
#pragma unroll
  for (int mi = 0; mi < 2; mi++)
#pragma unroll
    for (int r = 0; r < 4; r++) {
      float l = l_acc[mi][r];
      l += __shfl_xor(l, 1);
      l += __shfl_xor(l, 2);
      l += __shfl_xor(l, 4);
      l += __shfl_xor(l, 8);
      float inv = 1.f / l;
      int row = q0 + w * 32 + mi * 16 + quad * 4 + r;
      size_t base = (size_t)(b * TT + row) * 512 + h * 64;
#pragma unroll
      for (int nt = 0; nt < 4; nt++)
        y[base + nt * 16 + l16] = f2bf(acc_o[mi][nt][r] * inv);
    }
}

extern "C" void kernel_launch(void* const* d_in, const int* in_sizes, int n_in,
                              void* d_out, int out_size, void* d_ws, size_t ws_size,
                              hipStream_t stream) {
  const float* x = (const float*)d_in[0];       // [2,4096,512]
  const float* w_attn = (const float*)d_in[1];  // [1536,512]
  const float* w_proj = (const float*)d_in[2];  // [512,512]
  float* out = (float*)d_out;                   // [2,4096,512] fp32

  u16* xb = (u16*)d_ws;
  u16* wab = xb + (size_t)8192 * 512;
  u16* wpb = wab + (size_t)1536 * 512;
  u16* qkv = wpb + (size_t)512 * 512;
  u16* yb = qkv + (size_t)8192 * 1536;

  cvt_all<<<5120, 256, 0, stream>>>(x, w_attn, w_proj, xb, wab, wpb);
  // PROFILING: reps=4 on the two suspects; outputs bitwise identical.
  // t(kernel) = dispatch dur_us / 4; counters now visible above fill cutoff.
  gemm256<<<192, 512, 0, stream>>>(xb, wab, qkv, 8192, 1536, 512, 4);
  attn_win<<<dim3(TT / 128, HH, BB), 256, 0, stream>>>(qkv, yb, 4);
  gemm_bt_n64<<<dim3(64, 8), 256, 0, stream>>>(yb, wpb, out, 8192, 512, 512);
}

// Round 6
// 126.637 us; speedup vs baseline: 1.7090x; 1.7090x over previous
//
#include <hip/hip_runtime.h>
#include <hip/hip_bf16.h>
#include <stdint.h>

#define BB 2
#define TT 4096
#define CC 512
#define HH 8
#define MEM 256

typedef unsigned short u16;
typedef __bf16 bf16x8 __attribute__((ext_vector_type(8)));
typedef float floatx4 __attribute__((ext_vector_type(4)));

__device__ inline u16 f2bf(float f) {  // RNE
  uint32_t u = __float_as_uint(f);
  uint32_t r = (u + 0x7fffu + ((u >> 16) & 1u)) >> 16;
  return (u16)r;
}
__device__ inline u16 f2bf_r(float f) {  // round-half-up (2 ops), p>=0 only
  return (u16)((__float_as_uint(f) + 0x8000u) >> 16);
}

__device__ inline void gld16(const u16* g, u16* lds) {
  __builtin_amdgcn_global_load_lds(
      (const __attribute__((address_space(1))) uint32_t*)g,
      (__attribute__((address_space(3))) uint32_t*)lds, 16, 0, 0);
}

#define BARM() asm volatile("" ::: "memory")

// ---------------- fused fp32 -> bf16 convert (x, w_attn, w_proj) ----------
__global__ __launch_bounds__(256) void cvt_all(const float* __restrict__ x,
                                               const float* __restrict__ wa,
                                               const float* __restrict__ wp,
                                               u16* __restrict__ xb,
                                               u16* __restrict__ wab,
                                               u16* __restrict__ wpb) {
  int i = blockIdx.x * 256 + threadIdx.x;  // chunk of 4 floats
  const float* s; u16* d; int off;
  if (i < 1048576) { s = x; d = xb; off = i; }
  else if (i < 1245184) { s = wa; d = wab; off = i - 1048576; }
  else { s = wp; d = wpb; off = i - 1245184; }
  float4 v = *reinterpret_cast<const float4*>(s + (size_t)off * 4);
  ushort4 o;
  o.x = f2bf(v.x); o.y = f2bf(v.y); o.z = f2bf(v.z); o.w = f2bf(v.w);
  *reinterpret_cast<ushort4*>(d + (size_t)off * 4) = o;
}

// ============ 256x192 4-phase GEMM: C[M,N] = A[M,K] * Bw[N,K]^T ============
// R5/R6: N-tile 192 -> grid = (8192/256)*(1536/192) = 32*8 = 256 blocks
// = exactly 1 block per CU (R4 counters: 192-block grid left 64 CUs idle,
// Occupancy 15%, MfmaUtil 24%). 512 thr = 8 waves (2M x 4N); per-wave
// 128x48 out = 8x3 frags. BK=64, 2 dbuf, LDS 112 KiB.
// Phases per K-tile: (MQ,NQ) = (0,0)(0,1)(1,0)(1,1); NQ0 = fn{0,1} (B rows
// g*48..+31), NQ1 = fn{2} (B rows g*48+32..+47). Stripe death: A-MQ0 after
// ph2, B-NQ0 after ph3. Stage schedule (loads/thread in parens):
//   ph1: A-MQ1(t+1)->other buf (2)   ph2: B-NQ1(t+1)->other buf (1)
//   ph3: A-MQ0(t+2)->THIS buf  (2)   ph4: B-NQ0(t+2)->THIS buf  (2)
// vmcnt(4) at ph4 retires exactly tile t+1's 7 loads, leaves t+2's 4 in
// flight. Tail (t>=nK-2) stages nothing and drains vmcnt(0). No deadlock.
// LDS: row-major stride 64, 16B-block b of row r at b ^ (r&7) (conflict-free
// ds_read_b128 frags; R4 confirmed SQ_LDS_BANK_CONFLICT == 0).
__device__ inline void stage_hA(const u16* __restrict__ G, u16* lds, int K,
                                int gr0, int koff, int half, int wv, int lane) {
#pragma unroll
  for (int j = 0; j < 2; j++) {
    int lrow = (j * 8 + wv) * 8 + (lane >> 3);                 // 0..127
    int row = (lrow & 63) + ((lrow >> 6) << 7) + (half << 6);  // {0-63,128-191}+64*half
    int blk = (lane & 7) ^ (row & 7);
    gld16(G + (size_t)(gr0 + row) * K + koff + blk * 8,
          lds + (size_t)row * 64 + (lane & 7) * 8);
  }
}
// B rows live in 48-row wave-groups; NQ0 stripe = rows g*48..g*48+31 (128
// rows, 2 loads/thr), NQ1 stripe = rows g*48+32..g*48+47 (64 rows, 1 load).
__device__ inline void stage_hB(const u16* __restrict__ G, u16* lds, int K,
                                int gr0, int koff, int half, int wv, int lane) {
  if (half == 0) {
#pragma unroll
    for (int j = 0; j < 2; j++) {
      int lrow = (j * 8 + wv) * 8 + (lane >> 3);  // 0..127
      int row = (lrow & 31) + (lrow >> 5) * 48;
      int blk = (lane & 7) ^ (row & 7);
      gld16(G + (size_t)(gr0 + row) * K + koff + blk * 8,
            lds + (size_t)row * 64 + (lane & 7) * 8);
    }
  } else {
    int lrow = wv * 8 + (lane >> 3);  // 0..63
    int row = 32 + (lrow & 15) + (lrow >> 4) * 48;
    int blk = (lane & 7) ^ (row & 7);
    gld16(G + (size_t)(gr0 + row) * K + koff + blk * 8,
          lds + (size_t)row * 64 + (lane & 7) * 8);
  }
}

#define PHASE(MQ, NQ, NF, STAGE, WAITV)                                        \
  {                                                                            \
    bf16x8 af[4][2], bfv[NF][2];                                               \
    _Pragma("unroll") for (int fm = 0; fm < 4; fm++) {                         \
      int row = wm * 128 + MQ * 64 + fm * 16 + l16;                            \
      const u16* p = Ad + (size_t)row * 64;                                    \
      af[fm][0] = *(const bf16x8*)(p + ((quad ^ (row & 7)) << 3));             \
      af[fm][1] = *(const bf16x8*)(p + (((4 + quad) ^ (row & 7)) << 3));       \
    }                                                                          \
    _Pragma("unroll") for (int fn = 0; fn < NF; fn++) {                        \
      int row = wn * 48 + NQ * 32 + fn * 16 + l16;                             \
      const u16* p = Bd + (size_t)row * 64;                                    \
      bfv[fn][0] = *(const bf16x8*)(p + ((quad ^ (row & 7)) << 3));            \
      bfv[fn][1] = *(const bf16x8*)(p + (((4 + quad) ^ (row & 7)) << 3));      \
    }                                                                          \
    STAGE;                                                                     \
    BARM();                                                                    \
    __builtin_amdgcn_s_barrier();                                              \
    asm volatile("s_waitcnt lgkmcnt(0)" ::: "memory");                         \
    __builtin_amdgcn_sched_barrier(0);                                         \
    __builtin_amdgcn_s_setprio(1);                                             \
    _Pragma("unroll") for (int fm = 0; fm < 4; fm++)                           \
      _Pragma("unroll") for (int fn = 0; fn < NF; fn++) {                      \
        acc[MQ * 4 + fm][NQ * 2 + fn] =                                        \
            __builtin_amdgcn_mfma_f32_16x16x32_bf16(                           \
                af[fm][0], bfv[fn][0], acc[MQ * 4 + fm][NQ * 2 + fn], 0, 0, 0);\
        acc[MQ * 4 + fm][NQ * 2 + fn] =                                        \
            __builtin_amdgcn_mfma_f32_16x16x32_bf16(                           \
                af[fm][1], bfv[fn][1], acc[MQ * 4 + fm][NQ * 2 + fn], 0, 0, 0);\
      }                                                                        \
    __builtin_amdgcn_s_setprio(0);                                             \
    WAITV;                                                                     \
    BARM();                                                                    \
    __builtin_amdgcn_s_barrier();                                              \
    BARM();                                                                    \
  }

__global__ __launch_bounds__(512, 2) void gemm256(const u16* __restrict__ A,
                                                  const u16* __restrict__ Bw,
                                                  u16* __restrict__ C,
                                                  int M, int N, int K) {
  __shared__ __align__(16) u16 As[2][256 * 64];
  __shared__ __align__(16) u16 Bs[2][192 * 64];
  const int tid = threadIdx.x;
  const int lane = tid & 63, wv = tid >> 6;
  const int quad = lane >> 4, l16 = lane & 15;
  const int wm = wv >> 2, wn = wv & 3;

  // bijective XCD swizzle (nwg % 8 == 0 here: 256)
  const int nbx = N / 192;
  const int nwg = (M >> 8) * nbx;
  int wg = blockIdx.x;
  if ((nwg & 7) == 0) wg = (wg & 7) * (nwg >> 3) + (wg >> 3);
  const int m0 = (wg / nbx) << 8, n0 = (wg % nbx) * 192;

  const int nK = K >> 6;
  floatx4 acc[8][3] = {};

  // prologue: tile0 full (7 loads) + tile1 {A-MQ0, B-NQ0} (4 loads)
  stage_hA(A, As[0], K, m0, 0, 0, wv, lane);
  stage_hA(A, As[0], K, m0, 0, 1, wv, lane);
  stage_hB(Bw, Bs[0], K, n0, 0, 0, wv, lane);
  stage_hB(Bw, Bs[0], K, n0, 0, 1, wv, lane);
  if (nK > 1) {
    stage_hA(A, As[1], K, m0, 64, 0, wv, lane);
    stage_hB(Bw, Bs[1], K, n0, 64, 0, wv, lane);
    asm volatile("s_waitcnt vmcnt(4)" ::: "memory");
  } else {
    asm volatile("s_waitcnt vmcnt(0)" ::: "memory");
  }
  BARM();
  __builtin_amdgcn_s_barrier();
  BARM();

  for (int t = 0; t < nK; ++t) {
    const int d = t & 1;
    u16* Ad = As[d]; u16* Bd = Bs[d];
    u16* An = As[d ^ 1]; u16* Bn = Bs[d ^ 1];
    const int k1 = (t + 1) << 6, k2 = (t + 2) << 6;

    PHASE(0, 0, 2, { if (t + 1 < nK) stage_hA(A, An, K, m0, k1, 1, wv, lane); }, {})
    PHASE(0, 1, 1, { if (t + 1 < nK) stage_hB(Bw, Bn, K, n0, k1, 1, wv, lane); }, {})
    PHASE(1, 0, 2, { if (t + 2 < nK) stage_hA(A, Ad, K, m0, k2, 0, wv, lane); }, {})
    PHASE(1, 1, 1, { if (t + 2 < nK) stage_hB(Bw, Bd, K, n0, k2, 0, wv, lane); },
          { if (t + 2 < nK) asm volatile("s_waitcnt vmcnt(4)" ::: "memory");
            else            asm volatile("s_waitcnt vmcnt(0)" ::: "memory"); })
  }

#pragma unroll
  for (int mi = 0; mi < 8; mi++) {
    int row = m0 + wm * 128 + mi * 16 + quad * 4;
#pragma unroll
    for (int ni = 0; ni < 3; ni++) {
      int col = n0 + wn * 48 + ni * 16 + l16;
#pragma unroll
      for (int r = 0; r < 4; r++)
        C[(size_t)(row + r) * N + col] = f2bf(acc[mi][ni][r]);
    }
  }
}

// ---------------- GEMM 128x64 (for N=512 proj: 512 blocks, 2/CU) ----------
__global__ __launch_bounds__(256) void gemm_bt_n64(const u16* __restrict__ A,
                                                   const u16* __restrict__ Bw,
                                                   float* __restrict__ C,
                                                   int M, int N, int K) {
  __shared__ __align__(16) u16 As[128 * 32];
  __shared__ __align__(16) u16 Bs[64 * 32];
  const int tid = threadIdx.x;
  const int w = tid >> 6, lane = tid & 63, quad = lane >> 4, l16 = lane & 15;
  const int m0 = blockIdx.x * 128, n0 = blockIdx.y * 64;

  floatx4 acc[2][4] = {};
  const int nK = K >> 5;
  for (int kb = 0; kb < nK; ++kb) {
    const int kof = kb * 32;
    {
      int c = tid;
      gld16(A + (size_t)(m0 + (c >> 2)) * K + kof + (c & 3) * 8, As + (size_t)c * 8);
      c = tid + 256;
      gld16(A + (size_t)(m0 + (c >> 2)) * K + kof + (c & 3) * 8, As + (size_t)c * 8);
      c = tid;
      gld16(Bw + (size_t)(n0 + (c >> 2)) * K + kof + (c & 3) * 8, Bs + (size_t)c * 8);
    }
    __syncthreads();
    bf16x8 af[2], bfr[4];
#pragma unroll
    for (int i = 0; i < 2; i++)
      af[i] = *reinterpret_cast<const bf16x8*>(&As[(w * 32 + i * 16 + l16) * 32 + quad * 8]);
#pragma unroll
    for (int i = 0; i < 4; i++)
      bfr[i] = *reinterpret_cast<const bf16x8*>(&Bs[(i * 16 + l16) * 32 + quad * 8]);
#pragma unroll
    for (int mi = 0; mi < 2; mi++)
#pragma unroll
      for (int ni = 0; ni < 4; ni++)
        acc[mi][ni] = __builtin_amdgcn_mfma_f32_16x16x32_bf16(af[mi], bfr[ni], acc[mi][ni], 0, 0, 0);
    __syncthreads();
  }
#pragma unroll
  for (int mi = 0; mi < 2; mi++) {
    int row = m0 + w * 32 + mi * 16 + quad * 4;
#pragma unroll
    for (int ni = 0; ni < 4; ni++) {
      int col = n0 + ni * 16 + l16;
#pragma unroll
      for (int r = 0; r < 4; r++)
        C[(size_t)(row + r) * N + col] = acc[mi][ni][r];
    }
  }
}

// ---------------- windowed flash attention, Tq=128 ----------------
// grid (T/128, H, B), 256 thr = 4 waves; wave w owns q rows [w*32, w*32+32)
// as 2 m-subtiles of 16. 6 key-tiles of 64 cover [q0-256, q0+128).
__global__ __launch_bounds__(256, 2) void attn_win(const u16* __restrict__ qkv,
                                                   u16* __restrict__ y) {
  const int q0 = blockIdx.x * 128;
  const int h = blockIdx.y;
  const int b = blockIdx.z;
  const int tid = threadIdx.x;
  const int w = tid >> 6, lane = tid & 63, quad = lane >> 4, l16 = lane & 15;

  __shared__ __align__(16) u16 Qs[128 * 64];  // row-stride 64, col-block swizzled
  __shared__ __align__(16) u16 Ks[64 * 64];   // same
  __shared__ __align__(16) u16 Vt[64 * 72];   // V^T, stride 72, col = key^(d&56)
  __shared__ __align__(16) u16 Ps[4][32 * 72];

  // stage Q (128x64), swizzled
  const size_t baseQ = ((size_t)(b * TT + q0)) * 1536 + h * 64;
#pragma unroll
  for (int j = 0; j < 4; j++) {
    int c = tid + j * 256, row = c >> 3, blk = (c & 7) ^ (row & 7);
    gld16(qkv + baseQ + (size_t)row * 1536 + blk * 8, Qs + (size_t)c * 8);
  }
  __syncthreads();
  bf16x8 qf[2][2];
#pragma unroll
  for (int mi = 0; mi < 2; mi++) {
    int row = w * 32 + mi * 16 + l16;  // row&7 == l16&7
    qf[mi][0] = *reinterpret_cast<const bf16x8*>(&Qs[row * 64 + (quad ^ (l16 & 7)) * 8]);
    qf[mi][1] = *reinterpret_cast<const bf16x8*>(&Qs[row * 64 + ((quad + 4) ^ (l16 & 7)) * 8]);
#pragma unroll
    for (int e = 0; e < 8; e++) {  // fold 1/sqrt(d)=0.125 (exact pow2)
      qf[mi][0][e] = qf[mi][0][e] * (__bf16)0.125f;
      qf[mi][1][e] = qf[mi][1][e] * (__bf16)0.125f;
    }
  }

  floatx4 acc_o[2][4] = {};
  float l_acc[2][4] = {{0.f, 0.f, 0.f, 0.f}, {0.f, 0.f, 0.f, 0.f}};

  const int s_min = (q0 >= 256) ? 0 : ((256 - q0) >> 6);
  const int key_v = tid >> 3, dc_v = tid & 7;       // this thread's V slot (half 0)
  const int key_v1 = (tid + 256) >> 3, dc_v1 = tid & 7;  // half 1

  // prefetch V regs for first tile
  uint4 vp0, vp1;
  {
    size_t baseV = ((size_t)(b * TT + (q0 - 256 + s_min * 64))) * 1536 + 1024 + h * 64;
    vp0 = *reinterpret_cast<const uint4*>(qkv + baseV + (size_t)key_v * 1536 + dc_v * 8);
    vp1 = *reinterpret_cast<const uint4*>(qkv + baseV + (size_t)key_v1 * 1536 + dc_v1 * 8);
  }

  for (int s = s_min; s < 6; ++s) {
    const int k0 = q0 - 256 + s * 64;
    // stage K (swizzled DMA)
    const size_t baseK = ((size_t)(b * TT + k0)) * 1536 + 512 + h * 64;
    {
      int c = tid, row = c >> 3, blk = (c & 7) ^ (row & 7);
      gld16(qkv + baseK + (size_t)row * 1536 + blk * 8, Ks + (size_t)c * 8);
      c = tid + 256; row = c >> 3; blk = (c & 7) ^ (row & 7);
      gld16(qkv + baseK + (size_t)row * 1536 + blk * 8, Ks + (size_t)c * 8);
    }
    // write V^T from prefetched regs: elem (d,key) at Vt[d*72 + (key^(d&56))]
    {
      u16 tmp[8];
      *reinterpret_cast<uint4*>(tmp) = vp0;
      int col = key_v ^ (dc_v * 8);
#pragma unroll
      for (int e = 0; e < 8; e++) Vt[(dc_v * 8 + e) * 72 + col] = tmp[e];
      *reinterpret_cast<uint4*>(tmp) = vp1;
      col = key_v1 ^ (dc_v1 * 8);
#pragma unroll
      for (int e = 0; e < 8; e++) Vt[(dc_v1 * 8 + e) * 72 + col] = tmp[e];
    }
    // prefetch next tile's V regs (land during compute phase)
    if (s < 5) {
      size_t baseV = ((size_t)(b * TT + k0 + 64)) * 1536 + 1024 + h * 64;
      vp0 = *reinterpret_cast<const uint4*>(qkv + baseV + (size_t)key_v * 1536 + dc_v * 8);
      vp1 = *reinterpret_cast<const uint4*>(qkv + baseV + (size_t)key_v1 * 1536 + dc_v1 * 8);
    }
    __syncthreads();

    // wave-uniform mask mode: 0 none, 1 mask hq>kq, 2 mask hq<kq, 3 dead
    int mode = 0;
    if (s == 0) mode = (w < 2) ? 1 : 3;
    else if (s == 1) mode = (w < 2) ? 0 : 1;
    else if (s == 4) mode = (w < 2) ? 2 : 0;
    else if (s == 5) mode = (w < 2) ? 3 : 2;

    if (mode != 3) {
      bf16x8 bfr[4][2];
#pragma unroll
      for (int nt = 0; nt < 4; nt++) {
        int krow = nt * 16 + l16;
        bfr[nt][0] = *reinterpret_cast<const bf16x8*>(&Ks[krow * 64 + (quad ^ (l16 & 7)) * 8]);
        bfr[nt][1] = *reinterpret_cast<const bf16x8*>(&Ks[krow * 64 + ((quad + 4) ^ (l16 & 7)) * 8]);
      }
      floatx4 sc[2][4] = {};
#pragma unroll
      for (int mi = 0; mi < 2; mi++)
#pragma unroll
        for (int nt = 0; nt < 4; nt++) {
          sc[mi][nt] = __builtin_amdgcn_mfma_f32_16x16x32_bf16(qf[mi][0], bfr[nt][0], sc[mi][nt], 0, 0, 0);
          sc[mi][nt] = __builtin_amdgcn_mfma_f32_16x16x32_bf16(qf[mi][1], bfr[nt][1], sc[mi][nt], 0, 0, 0);
        }
      const int hqb = (w & 1) * 32 + quad * 4;  // + mi*16 + r
      if (mode == 1) {
#pragma unroll
        for (int mi = 0; mi < 2; mi++)
#pragma unroll
          for (int nt = 0; nt < 4; nt++)
#pragma unroll
            for (int r = 0; r < 4; r++)
              if (hqb + mi * 16 + r > nt * 16 + l16) sc[mi][nt][r] = -1e30f;
      } else if (mode == 2) {
#pragma unroll
        for (int mi = 0; mi < 2; mi++)
#pragma unroll
          for (int nt = 0; nt < 4; nt++)
#pragma unroll
            for (int r = 0; r < 4; r++)
              if (hqb + mi * 16 + r < nt * 16 + l16) sc[mi][nt][r] = -1e30f;
      }
      // fixed-max softmax: p = exp(s - 4); per-lane l accumulation
#pragma unroll
      for (int mi = 0; mi < 2; mi++)
#pragma unroll
        for (int nt = 0; nt < 4; nt++)
#pragma unroll
          for (int r = 0; r < 4; r++) {
            float p = __expf(sc[mi][nt][r] - 4.0f);
            l_acc[mi][r] += p;
            Ps[w][(mi * 16 + quad * 4 + r) * 72 + nt * 16 + l16] = f2bf_r(p);
          }
      // O += P*V
#pragma unroll
      for (int mi = 0; mi < 2; mi++)
#pragma unroll
        for (int ki = 0; ki < 2; ki++) {
          bf16x8 pf = *reinterpret_cast<const bf16x8*>(
              &Ps[w][(mi * 16 + l16) * 72 + ki * 32 + quad * 8]);
#pragma unroll
          for (int nt = 0; nt < 4; nt++) {
            int d = nt * 16 + l16;
            bf16x8 vf = *reinterpret_cast<const bf16x8*>(
                &Vt[d * 72 + ((ki * 32 + quad * 8) ^ (d & 56))]);
            acc_o[mi][nt] = __builtin_amdgcn_mfma_f32_16x16x32_bf16(pf, vf, acc_o[mi][nt], 0, 0, 0);
          }
        }
    }
    __syncthreads();
  }
  // epilogue: reduce l across the quad-row's 16 lanes, normalize, write
#pragma unroll
  for (int mi = 0; mi < 2; mi++)
#pragma unroll
    for (int r = 0; r < 4; r++) {
      float l = l_acc[mi][r];
      l += __shfl_xor(l, 1);
      l += __shfl_xor(l, 2);
      l += __shfl_xor(l, 4);
      l += __shfl_xor(l, 8);
      float inv = 1.f / l;
      int row = q0 + w * 32 + mi * 16 + quad * 4 + r;
      size_t base = (size_t)(b * TT + row) * 512 + h * 64;
#pragma unroll
      for (int nt = 0; nt < 4; nt++)
        y[base + nt * 16 + l16] = f2bf(acc_o[mi][nt][r] * inv);
    }
}

extern "C" void kernel_launch(void* const* d_in, const int* in_sizes, int n_in,
                              void* d_out, int out_size, void* d_ws, size_t ws_size,
                              hipStream_t stream) {
  const float* x = (const float*)d_in[0];       // [2,4096,512]
  const float* w_attn = (const float*)d_in[1];  // [1536,512]
  const float* w_proj = (const float*)d_in[2];  // [512,512]
  float* out = (float*)d_out;                   // [2,4096,512] fp32

  u16* xb = (u16*)d_ws;
  u16* wab = xb + (size_t)8192 * 512;
  u16* wpb = wab + (size_t)1536 * 512;
  u16* qkv = wpb + (size_t)512 * 512;
  u16* yb = qkv + (size_t)8192 * 1536;

  cvt_all<<<5120, 256, 0, stream>>>(x, w_attn, w_proj, xb, wab, wpb);
  gemm256<<<256, 512, 0, stream>>>(xb, wab, qkv, 8192, 1536, 512);
  attn_win<<<dim3(TT / 128, HH, BB), 256, 0, stream>>>(qkv, yb);
  gemm_bt_n64<<<dim3(64, 8), 256, 0, stream>>>(yb, wpb, out, 8192, 512, 512);
}